// Round 22
// baseline (188.296 us; speedup 1.0000x reference)
//
#include <hip/hip_runtime.h>
#include <hip/hip_bf16.h>

#define BB 8
#define NN 16384
#define CC 128

typedef __attribute__((ext_vector_type(8))) short bf16x8;
typedef __attribute__((ext_vector_type(4))) short short4v;
typedef __attribute__((ext_vector_type(4))) float f32x4;

__device__ __forceinline__ unsigned short f2bf(float f) {
    union { float f; unsigned u; } v; v.f = f;
    unsigned r = v.u + 0x7fffu + ((v.u >> 16) & 1u);
    return (unsigned short)(r >> 16);
}
__device__ __forceinline__ float bf2f(unsigned short h) {
    union { unsigned u; float f; } v; v.u = ((unsigned)h) << 16;
    return v.f;
}
// truncating hi/lo split: lo captures the residual, RNE on hi unnecessary
__device__ __forceinline__ void split_trunc(float f, short& hi, short& lo) {
    union { float f; unsigned u; } v; v.f = f;
    const unsigned short hu = (unsigned short)(v.u >> 16);
    union { unsigned u; float f; } hf; hf.u = ((unsigned)hu) << 16;
    union { float f; unsigned u; } r; r.f = f - hf.f;
    hi = (short)hu;
    lo = (short)(r.u >> 16);
}

// ---------------------------------------------------------------------------
// W prep: split Wq/Wkv/Wproj into bf16 hi/lo (blocks 0-47); block 48
// precomputes sps[c] = 1/softplus(scale[c]). grid 49, block 256.
// ---------------------------------------------------------------------------
__global__ __launch_bounds__(256) void wprep_kernel(
    const float* __restrict__ Wq, const float* __restrict__ Wkv,
    const float* __restrict__ Wp, const float* __restrict__ scale,
    unsigned short* __restrict__ whi, unsigned short* __restrict__ wlo,
    float* __restrict__ sps)
{
    const int bid = blockIdx.x;
    if (bid == 48) {
        if (threadIdx.x < 128)
            sps[threadIdx.x] = 1.f / log1pf(expf(scale[threadIdx.x]));
        return;
    }
    const int mat = bid >> 4;
    const float* src = (mat == 0) ? Wq : ((mat == 1) ? Wkv : Wp);
    const int off = (bid & 15) * 1024 + threadIdx.x * 4;
    const float4 v = *(const float4*)(src + off);
    float f[4] = {v.x, v.y, v.z, v.w};
    short4v hv, lv;
#pragma unroll
    for (int j = 0; j < 4; ++j) {
        short h, lo2;
        split_trunc(f[j], h, lo2);
        hv[j] = h; lv[j] = lo2;
    }
    *(short4v*)(whi + mat * 16384 + off) = hv;
    *(short4v*)(wlo + mat * 16384 + off) = lv;
}

// ---------------------------------------------------------------------------
// kproj (R17, unchanged): x @ Wkv.T + pos + focusing -> k_t + ksum.
// Runs FIRST so kbar is ready before qproj. grid 1024, block 256.
// ---------------------------------------------------------------------------
__global__ __launch_bounds__(256, 2) void kproj_kernel(
    const float* __restrict__ x, const unsigned short* __restrict__ whi,
    const unsigned short* __restrict__ wlo,
    const float* __restrict__ sps, const float* __restrict__ pos_enc,
    unsigned short* __restrict__ ktout, float* __restrict__ partial2)
{
    __shared__ __align__(16) char wsm[65536];
    __shared__ float wpart[4][128];

    const int tid  = threadIdx.x;
    const int w    = tid >> 6;
    const int l    = tid & 63;
    const int blk  = blockIdx.x;
    const int tok0 = blk * 128;
    const int tokb = (blk & 127) * 128;

    bf16x8 xh[2][4], xl[2][4];
#pragma unroll
    for (int n = 0; n < 2; ++n) {
        const int r = w * 32 + n * 16 + (l & 15);
        const float* rowp = x + (tok0 + r) * 128 + (l >> 4) * 8;
#pragma unroll
        for (int kt = 0; kt < 4; ++kt) {
            const f32x4 a = *(const f32x4*)(rowp + kt * 32);
            const f32x4 b = *(const f32x4*)(rowp + kt * 32 + 4);
            const float f[8] = {a[0], a[1], a[2], a[3], b[0], b[1], b[2], b[3]};
            bf16x8 hv, lv;
#pragma unroll
            for (int j = 0; j < 8; ++j) {
                short h, lo2;
                split_trunc(f[j], h, lo2);
                hv[j] = h; lv[j] = lo2;
            }
            xh[n][kt] = hv; xl[n][kt] = lv;
        }
    }

#pragma unroll
    for (int it = 0; it < 16; ++it) {
        const int flat = it * 256 + tid;
        const int arr  = flat >> 11;
        const int c    = (flat >> 4) & 127;
        const int g    = flat & 15;
        const unsigned short* src = (arr ? wlo : whi) + 16384 + c * 128 + g * 8;
        const int dst = arr * 32768 + c * 256 + ((g * 16) ^ ((c & 7) << 4));
        *(bf16x8*)(wsm + dst) = *(const bf16x8*)src;
    }
    __syncthreads();

    const int crow = (l >> 4) * 4;
    f32x4 acc[8][2];
#pragma unroll
    for (int m = 0; m < 8; ++m)
#pragma unroll
        for (int n = 0; n < 2; ++n) acc[m][n] = (f32x4)0.f;

#pragma unroll
    for (int m = 0; m < 8; ++m) {
        const int c = m * 16 + (l & 15);
        const int sw = (c & 7) << 4;
        bf16x8 ah[4], al[4];
#pragma unroll
        for (int kt = 0; kt < 4; ++kt) {
            const int fo = c * 256 + ((kt * 64 + (l >> 4) * 16) ^ sw);
            ah[kt] = *(const bf16x8*)(wsm + fo);
            al[kt] = *(const bf16x8*)(wsm + 32768 + fo);
        }
#pragma unroll
        for (int n = 0; n < 2; ++n)
#pragma unroll
            for (int kt = 0; kt < 4; ++kt) {
                acc[m][n] = __builtin_amdgcn_mfma_f32_16x16x32_bf16(ah[kt], xh[n][kt], acc[m][n], 0, 0, 0);
                acc[m][n] = __builtin_amdgcn_mfma_f32_16x16x32_bf16(ah[kt], xl[n][kt], acc[m][n], 0, 0, 0);
                acc[m][n] = __builtin_amdgcn_mfma_f32_16x16x32_bf16(al[kt], xh[n][kt], acc[m][n], 0, 0, 0);
            }
    }
    __syncthreads();

#pragma unroll
    for (int m = 0; m < 8; ++m) {
        const float4 is4 = *(const float4*)(sps + m * 16 + crow);
        const float is[4] = {is4.x, is4.y, is4.z, is4.w};
#pragma unroll
        for (int n = 0; n < 2; ++n) {
            const int t = tokb + w * 32 + n * 16 + (l & 15);
            const float4 p = *(const float4*)(pos_enc + t * 128 + m * 16 + crow);
            const float pe[4] = {p.x, p.y, p.z, p.w};
#pragma unroll
            for (int j = 0; j < 4; ++j)
                acc[m][n][j] = (fmaxf(acc[m][n][j] + pe[j], 0.f) + 1e-6f) * is[j];
        }
    }
    float fkn[2];
#pragma unroll
    for (int n = 0; n < 2; ++n) {
        float s2 = 0.f, s6 = 0.f;
#pragma unroll
        for (int m = 0; m < 8; ++m)
#pragma unroll
            for (int j = 0; j < 4; ++j) {
                const float v = acc[m][n][j], v2 = v * v;
                s2 += v2; s6 += v2 * v2 * v2;
            }
        s2 += __shfl_xor(s2, 16); s6 += __shfl_xor(s6, 16);
        s2 += __shfl_xor(s2, 32); s6 += __shfl_xor(s6, 32);
        fkn[n] = sqrtf(s2 / s6);
    }
#pragma unroll
    for (int m = 0; m < 8; ++m)
#pragma unroll
        for (int n = 0; n < 2; ++n)
#pragma unroll
            for (int j = 0; j < 4; ++j) {
                const float v = acc[m][n][j];
                acc[m][n][j] = v * v * v * fkn[n];
            }
#pragma unroll
    for (int m = 0; m < 8; ++m)
#pragma unroll
        for (int j = 0; j < 4; ++j) {
            float s = acc[m][0][j] + acc[m][1][j];
            s += __shfl_xor(s, 1); s += __shfl_xor(s, 2);
            s += __shfl_xor(s, 4); s += __shfl_xor(s, 8);
            if ((l & 15) == 0) wpart[w][m * 16 + crow + j] = s;
        }

#pragma unroll
    for (int m = 0; m < 8; ++m)
#pragma unroll
        for (int n = 0; n < 2; ++n)
#pragma unroll
            for (int j = 0; j < 4; ++j) {
                const int ch = m * 16 + crow + j;
                const int tl = w * 32 + n * 16 + (l & 15);
                *(unsigned short*)(wsm + ch * 264 + tl * 2) = f2bf(acc[m][n][j]);
            }
    __syncthreads();
    {
        const int bb = blk >> 7;
        unsigned* ktp = (unsigned*)ktout;
#pragma unroll
        for (int it = 0; it < 32; ++it) {
            const int idx = it * 256 + tid;
            const int row = idx >> 6;
            const int col = idx & 63;
            const unsigned v = *(unsigned*)(wsm + row * 264 + col * 4);
            ktp[(size_t)(bb * 128 + row) * 8192 + (blk & 127) * 64 + col] = v;
        }
    }
    __syncthreads();
    if (tid < 128)
        partial2[blk * 128 + tid] = wpart[0][tid] + wpart[1][tid] +
                                    wpart[2][tid] + wpart[3][tid];
}

// ---------------------------------------------------------------------------
// reduce_k: kbar from kproj partials. grid 8, block 256.
// ---------------------------------------------------------------------------
__global__ __launch_bounds__(256) void reducek_kernel(
    const float* __restrict__ partial2, float* __restrict__ kbar)
{
    const int b = blockIdx.x;
    const int tid = threadIdx.x;
    if (tid < 128) {
        float s = 0.f;
        for (int t = 0; t < 128; ++t)
            s += partial2[(b * 128 + t) * 128 + tid];
        kbar[b * 128 + tid] = s * (1.f / 16384.f);
    }
}

// ---------------------------------------------------------------------------
// qproj v2 (R21, unchanged): x @ Wq.T + focusing; z inline from fp32 accs;
// G partials via shuffle algebra. grid 1024, block 256.
// ---------------------------------------------------------------------------
__global__ __launch_bounds__(256, 2) void qproj_kernel(
    const float* __restrict__ x, const unsigned short* __restrict__ whi,
    const unsigned short* __restrict__ wlo, const float* __restrict__ w_g,
    const float* __restrict__ sps, const float* __restrict__ kbar,
    float* __restrict__ z, float* __restrict__ partial1)
{
    __shared__ __align__(16) char wsm[65536];
    __shared__ float wpart[4][132];

    const int tid  = threadIdx.x;
    const int w    = tid >> 6;
    const int l    = tid & 63;
    const int blk  = blockIdx.x;
    const int tok0 = blk * 128;
    const int bq   = blk >> 7;
    const int tokb = (blk & 127) * 128;

    bf16x8 xh[2][4], xl[2][4];
#pragma unroll
    for (int n = 0; n < 2; ++n) {
        const int r = w * 32 + n * 16 + (l & 15);
        const float* rowp = x + (tok0 + r) * 128 + (l >> 4) * 8;
#pragma unroll
        for (int kt = 0; kt < 4; ++kt) {
            const f32x4 a = *(const f32x4*)(rowp + kt * 32);
            const f32x4 b = *(const f32x4*)(rowp + kt * 32 + 4);
            const float f[8] = {a[0], a[1], a[2], a[3], b[0], b[1], b[2], b[3]};
            bf16x8 hv, lv;
#pragma unroll
            for (int j = 0; j < 8; ++j) {
                short h, lo2;
                split_trunc(f[j], h, lo2);
                hv[j] = h; lv[j] = lo2;
            }
            xh[n][kt] = hv; xl[n][kt] = lv;
        }
    }

#pragma unroll
    for (int it = 0; it < 16; ++it) {
        const int flat = it * 256 + tid;
        const int arr  = flat >> 11;
        const int c    = (flat >> 4) & 127;
        const int g    = flat & 15;
        const unsigned short* src = (arr ? wlo : whi) + c * 128 + g * 8;
        const int dst = arr * 32768 + c * 256 + ((g * 16) ^ ((c & 7) << 4));
        *(bf16x8*)(wsm + dst) = *(const bf16x8*)src;
    }
    __syncthreads();

    const int crow = (l >> 4) * 4;
    f32x4 acc[8][2];
#pragma unroll
    for (int m = 0; m < 8; ++m)
#pragma unroll
        for (int n = 0; n < 2; ++n) acc[m][n] = (f32x4)0.f;

#pragma unroll
    for (int m = 0; m < 8; ++m) {
        const int c = m * 16 + (l & 15);
        const int sw = (c & 7) << 4;
        bf16x8 ah[4], al[4];
#pragma unroll
        for (int kt = 0; kt < 4; ++kt) {
            const int fo = c * 256 + ((kt * 64 + (l >> 4) * 16) ^ sw);
            ah[kt] = *(const bf16x8*)(wsm + fo);
            al[kt] = *(const bf16x8*)(wsm + 32768 + fo);
        }
#pragma unroll
        for (int n = 0; n < 2; ++n)
#pragma unroll
            for (int kt = 0; kt < 4; ++kt) {
                acc[m][n] = __builtin_amdgcn_mfma_f32_16x16x32_bf16(ah[kt], xh[n][kt], acc[m][n], 0, 0, 0);
                acc[m][n] = __builtin_amdgcn_mfma_f32_16x16x32_bf16(ah[kt], xl[n][kt], acc[m][n], 0, 0, 0);
                acc[m][n] = __builtin_amdgcn_mfma_f32_16x16x32_bf16(al[kt], xh[n][kt], acc[m][n], 0, 0, 0);
            }
    }

#pragma unroll
    for (int m = 0; m < 8; ++m) {
        const float4 is4 = *(const float4*)(sps + m * 16 + crow);
        const float is[4] = {is4.x, is4.y, is4.z, is4.w};
#pragma unroll
        for (int n = 0; n < 2; ++n)
#pragma unroll
            for (int j = 0; j < 4; ++j)
                acc[m][n][j] = (fmaxf(acc[m][n][j], 0.f) + 1e-6f) * is[j];
    }
    float fqn[2];
#pragma unroll
    for (int n = 0; n < 2; ++n) {
        float s2 = 0.f, s6 = 0.f;
#pragma unroll
        for (int m = 0; m < 8; ++m)
#pragma unroll
            for (int j = 0; j < 4; ++j) {
                const float v = acc[m][n][j], v2 = v * v;
                s2 += v2; s6 += v2 * v2 * v2;
            }
        s2 += __shfl_xor(s2, 16); s6 += __shfl_xor(s6, 16);
        s2 += __shfl_xor(s2, 32); s6 += __shfl_xor(s6, 32);
        fqn[n] = sqrtf(s2 / s6);
    }
#pragma unroll
    for (int m = 0; m < 8; ++m)
#pragma unroll
        for (int n = 0; n < 2; ++n)
#pragma unroll
            for (int j = 0; j < 4; ++j) {
                const float v = acc[m][n][j];
                acc[m][n][j] = v * v * v * fqn[n];
            }

#pragma unroll
    for (int m = 0; m < 8; ++m) {
        const float4 kb = *(const float4*)(kbar + bq * 128 + m * 16 + crow);
        const float kbv[4] = {kb.x, kb.y, kb.z, kb.w};
        float dm0 = 0.f, dm1 = 0.f;
#pragma unroll
        for (int j = 0; j < 4; ++j) {
            dm0 += acc[m][0][j] * kbv[j];
            dm1 += acc[m][1][j] * kbv[j];
        }
        dm0 += __shfl_xor(dm0, 16); dm0 += __shfl_xor(dm0, 32);
        dm1 += __shfl_xor(dm1, 16); dm1 += __shfl_xor(dm1, 32);
        if (l < 16) {
            const int t0 = tokb + w * 32 + l;
            z[((size_t)bq * 8 + m) * NN + t0]      = 1.f / (dm0 + 1e-6f);
            z[((size_t)bq * 8 + m) * NN + t0 + 16] = 1.f / (dm1 + 1e-6f);
        }
    }

    float d0 = 0.f, d1 = 0.f;
#pragma unroll
    for (int m = 0; m < 8; ++m) {
        const float4 wgv = *(const float4*)(w_g + m * 16 + crow);
#pragma unroll
        for (int j = 0; j < 4; ++j) {
            const float wg = (j == 0) ? wgv.x : (j == 1) ? wgv.y : (j == 2) ? wgv.z : wgv.w;
            d0 += acc[m][0][j] * wg;
            d1 += acc[m][1][j] * wg;
        }
    }
    d0 += __shfl_xor(d0, 16); d0 += __shfl_xor(d0, 32);
    d1 += __shfl_xor(d1, 16); d1 += __shfl_xor(d1, 32);
    const float ap0 = 0.25f * d0, ap1 = 0.25f * d1;

    float ssa = ap0 * ap0 + ap1 * ap1;
    ssa += __shfl_xor(ssa, 1); ssa += __shfl_xor(ssa, 2);
    ssa += __shfl_xor(ssa, 4); ssa += __shfl_xor(ssa, 8);
    if (l == 0) wpart[w][128] = ssa;

#pragma unroll
    for (int m = 0; m < 8; ++m)
#pragma unroll
        for (int j = 0; j < 4; ++j) {
            float g = ap0 * acc[m][0][j] + ap1 * acc[m][1][j];
            g += __shfl_xor(g, 1); g += __shfl_xor(g, 2);
            g += __shfl_xor(g, 4); g += __shfl_xor(g, 8);
            if ((l & 15) == 0) wpart[w][m * 16 + crow + j] = g;
        }
    __syncthreads();
    float* pblk = partial1 + blk * 132;
    if (tid < 128)
        pblk[tid] = wpart[0][tid] + wpart[1][tid] + wpart[2][tid] + wpart[3][tid];
    else if (tid == 128)
        pblk[128] = wpart[0][128] + wpart[1][128] + wpart[2][128] + wpart[3][128];
}

// ---------------------------------------------------------------------------
// reduce_g: G from qproj partials (+ssa normalization). grid 8, block 256.
// ---------------------------------------------------------------------------
__global__ __launch_bounds__(256) void reduceg_kernel(
    const float* __restrict__ partial1, float* __restrict__ G)
{
    const int b = blockIdx.x;
    const int tid = threadIdx.x;
    __shared__ float tmp[4];

    float ssa = (tid < 128) ? partial1[(b * 128 + tid) * 132 + 128] : 0.f;
#pragma unroll
    for (int o = 32; o >= 1; o >>= 1) ssa += __shfl_xor(ssa, o);
    if ((tid & 63) == 0) tmp[tid >> 6] = ssa;
    __syncthreads();
    const float anorm = fmaxf(sqrtf(tmp[0] + tmp[1] + tmp[2] + tmp[3]), 1e-12f);
    const float inv_a = 1.f / anorm;

    if (tid < 128) {
        float g = 0.f;
        for (int t = 0; t < 128; ++t)
            g += partial1[(b * 128 + t) * 132 + tid];
        G[b * 128 + tid] = g * inv_a;
    }
}

// ---------------------------------------------------------------------------
// scp v7: conv dy-slices STAGED IN LDS (R21 counters: scp latency-bound at
// all-pipes-idle; the 80 scattered 16B/32KB-stride loads per thread were the
// serialized chain). Per dy: block cooperatively stages kt[b,:,yy,:] (32KB,
// coalesced 256B-per-row segments, 8 independent loads/thread) into a
// 264B-pitch LDS slab, then conv consumes from LDS. Staging slab reuses the
// proj-tile region (barrier-separated). grid 1024, block 256.
// ---------------------------------------------------------------------------
__global__ __launch_bounds__(256, 2) void scp_kernel(
    float* __restrict__ out, const unsigned short* __restrict__ kt,
    const float* __restrict__ z, const float* __restrict__ G,
    const unsigned short* __restrict__ whi, const unsigned short* __restrict__ wlo,
    const float* __restrict__ bp, const float* __restrict__ dwc_w,
    const float* __restrict__ dwc_b)
{
    __shared__ __align__(16) char smem[33792];   // stage [128][264B] / tile 32KB
    __shared__ float wct[25][16];
    __shared__ float bi[16];
    __shared__ float Gs;

    const int tid  = threadIdx.x;
    const int bid0 = blockIdx.x;
    const int bid  = (bid0 & 7) * 128 + (bid0 >> 3);
    const int cc   = bid & 127;
    const int b    = bid >> 7;
    const int n0   = bid * 128;

    for (int i = tid; i < 400; i += 256)
        wct[i >> 4][i & 15] = dwc_w[(i & 15) * 25 + (i >> 4)];
    if (tid < 16) bi[tid] = dwc_b[tid];
    if (tid == 0) Gs = G[b * 128 + cc];
    __syncthreads();

    const int ch4 = tid >> 3;         // channel quad 0..31
    const int xg  = tid & 7;          // x-group 0..7

    float acc[4][16];
#pragma unroll
    for (int c = 0; c < 4; ++c)
#pragma unroll
        for (int i = 0; i < 16; ++i) acc[c][i] = 0.f;

    for (int dy = 0; dy < 5; ++dy) {
        const int yy = cc + dy - 2;
        if (yy < 0 || yy > 127) continue;      // block-uniform: barriers safe
        __syncthreads();                        // prior consume done
        // ---- stage slice kt[b, :, yy, :] -> smem[ch][264B] ----
#pragma unroll
        for (int it = 0; it < 8; ++it) {
            const int flat = it * 256 + tid;    // 0..2047
            const int ch = flat >> 4;
            const int c4 = flat & 15;
            const bf16x8 v = *(const bf16x8*)(kt + ((size_t)b * 128 + ch) * NN
                                              + yy * 128 + c4 * 8);
            *(bf16x8*)(smem + ch * 264 + c4 * 16) = v;
        }
        __syncthreads();
        // ---- consume from LDS ----
#pragma unroll
        for (int c = 0; c < 4; ++c) {
            const int ch = ch4 * 4 + c;
            const int base = ch * 264 + xg * 32 - 16;  // byte of position xg*16-8
            float wf[32];
            if (xg == 0) {
#pragma unroll
                for (int e = 0; e < 8; ++e) wf[e] = 0.f;
#pragma unroll
                for (int q = 1; q < 4; ++q) {
                    const bf16x8 v = *(const bf16x8*)(smem + base + q * 16);
#pragma unroll
                    for (int e = 0; e < 8; ++e)
                        wf[q * 8 + e] = bf2f((unsigned short)v[e]);
                }
            } else if (xg == 7) {
#pragma unroll
                for (int q = 0; q < 3; ++q) {
                    const bf16x8 v = *(const bf16x8*)(smem + base + q * 16);
#pragma unroll
                    for (int e = 0; e < 8; ++e)
                        wf[q * 8 + e] = bf2f((unsigned short)v[e]);
                }
#pragma unroll
                for (int e = 24; e < 32; ++e) wf[e] = 0.f;
            } else {
#pragma unroll
                for (int q = 0; q < 4; ++q) {
                    const bf16x8 v = *(const bf16x8*)(smem + base + q * 16);
#pragma unroll
                    for (int e = 0; e < 8; ++e)
                        wf[q * 8 + e] = bf2f((unsigned short)v[e]);
                }
            }
            const int d = ch & 15;
#pragma unroll
            for (int dx = 0; dx < 5; ++dx) {
                const float wv = wct[dy * 5 + dx][d];
#pragma unroll
                for (int i = 0; i < 16; ++i)
                    acc[c][i] += wv * wf[i + dx + 6];
            }
        }
    }
    __syncthreads();   // all consumes done; smem becomes the proj tile

    // ---- phase 2: u-part inline + conv + bias -> single-bf16 tile ----
    const float Gcc = Gs;
    const unsigned short* kub = kt + ((size_t)b * 128 + cc) * NN;
    const float* zr = z + ((size_t)b * 8 + (cc >> 4)) * NN;
    const int dbase = (ch4 & 3) * 4;
    const float4 b4 = *(const float4*)(&bi[dbase]);
    const float bv[4] = {b4.x, b4.y, b4.z, b4.w};
#pragma unroll
    for (int i = 0; i < 16; ++i) {
        const int r = xg * 16 + i;
        const int toks = r * 128 + ch4 * 4;
        const short4v ku4 = *(const short4v*)(kub + toks);
        const float4 z4 = *(const float4*)(zr + toks);
        const float zz[4] = {z4.x, z4.y, z4.z, z4.w};
        short4v hv;
#pragma unroll
        for (int c = 0; c < 4; ++c) {
            const float f = Gcc * bf2f((unsigned short)ku4[c]) * zz[c] + acc[c][i] + bv[c];
            hv[c] = (short)f2bf(f);
        }
        const int swz = (((r & 7) ^ ((r >> 3) & 7)) << 4);
        const int ad = r * 256 + (((ch4 >> 1) * 16) ^ swz) + (ch4 & 1) * 8;
        *(short4v*)(smem + ad) = hv;
    }
    __syncthreads();

    // ---- proj MFMA (A = Wproj hi/lo from L2, B = single-bf16 tile) ----
    const int w  = tid >> 6;
    const int ll = tid & 63;
    bf16x8 xh[2][4];
    {
        const int lg16 = (ll >> 4) * 16;
#pragma unroll
        for (int n = 0; n < 2; ++n) {
            const int r = w * 32 + n * 16 + (ll & 15);
            const int rb = r * 256;
            const int swz = (((r & 7) ^ ((r >> 3) & 7)) << 4);
#pragma unroll
            for (int kt2 = 0; kt2 < 4; ++kt2)
                xh[n][kt2] = *(bf16x8*)(smem + rb + ((kt2 * 64 + lg16) ^ swz));
        }
    }
    const int crow = (ll >> 4) * 4;
    f32x4 pacc[8][2];
#pragma unroll
    for (int m = 0; m < 8; ++m)
#pragma unroll
        for (int n = 0; n < 2; ++n) pacc[m][n] = (f32x4)0.f;

#pragma unroll
    for (int m = 0; m < 8; ++m) {
        const int c = m * 16 + (ll & 15);
        bf16x8 ah[4], al[4];
#pragma unroll
        for (int kt2 = 0; kt2 < 4; ++kt2) {
            const int off = 32768 + c * 128 + kt2 * 32 + (ll >> 4) * 8;
            ah[kt2] = *(const bf16x8*)(whi + off);
            al[kt2] = *(const bf16x8*)(wlo + off);
        }
#pragma unroll
        for (int n = 0; n < 2; ++n)
#pragma unroll
            for (int kt2 = 0; kt2 < 4; ++kt2) {
                pacc[m][n] = __builtin_amdgcn_mfma_f32_16x16x32_bf16(ah[kt2], xh[n][kt2], pacc[m][n], 0, 0, 0);
                pacc[m][n] = __builtin_amdgcn_mfma_f32_16x16x32_bf16(al[kt2], xh[n][kt2], pacc[m][n], 0, 0, 0);
            }
    }

    // ---- bias + transpose (wave-private 8KB, two sub-phases) + store ----
#pragma unroll
    for (int m = 0; m < 8; ++m) {
        const float4 bq = *(const float4*)(bp + m * 16 + crow);
        const float bb[4] = {bq.x, bq.y, bq.z, bq.w};
#pragma unroll
        for (int n = 0; n < 2; ++n)
#pragma unroll
            for (int j = 0; j < 4; ++j) pacc[m][n][j] += bb[j];
    }
    __syncthreads();
#pragma unroll
    for (int n = 0; n < 2; ++n) {
        const int t = ll & 15;
        const int rb = w * 8192 + t * 512;
#pragma unroll
        for (int m = 0; m < 8; ++m) {
            const int ad = rb + (((m * 16 + crow) * 4) ^ ((t & 7) << 4));
            *(f32x4*)(smem + ad) = pacc[m][n];
        }
        asm volatile("s_waitcnt lgkmcnt(0)" ::: "memory");
#pragma unroll
        for (int j = 0; j < 8; ++j) {
            const int fid = j * 64 + ll;
            const int row = fid >> 5;
            const int c4  = fid & 31;
            const int rb3 = w * 8192 + row * 512;
            const f32x4 v = *(f32x4*)(smem + rb3 + ((c4 * 16) ^ ((row & 7) << 4)));
            *(f32x4*)(out + (n0 + w * 32 + n * 16 + row) * 128 + c4 * 4) = v;
        }
    }
}

// ---------------------------------------------------------------------------
extern "C" void kernel_launch(void* const* d_in, const int* in_sizes, int n_in,
                              void* d_out, int out_size, void* d_ws, size_t ws_size,
                              hipStream_t stream)
{
    const float* x       = (const float*)d_in[0];
    const float* Wq      = (const float*)d_in[1];
    const float* Wkv     = (const float*)d_in[2];
    const float* Wproj   = (const float*)d_in[3];
    const float* bproj   = (const float*)d_in[4];
    const float* w_g     = (const float*)d_in[5];
    const float* scale   = (const float*)d_in[6];
    const float* pos_enc = (const float*)d_in[7];
    const float* dwc_w   = (const float*)d_in[8];
    const float* dwc_b   = (const float*)d_in[9];
    float* out = (float*)d_out;

    char* ws = (char*)d_ws;
    float* partial1 = (float*)(ws);                           // 540672 B
    float* partial2 = (float*)(ws + 540672);                  // 524288 B
    float* G        = (float*)(ws + 1064960);                 // 4096 B
    float* kbar     = (float*)(ws + 1069056);                 // 4096 B
    unsigned short* whi = (unsigned short*)(ws + 1073152);    // 98304 B
    unsigned short* wlo = (unsigned short*)(ws + 1171456);    // 98304 B
    float* sps      = (float*)(ws + 1269760);                 // 512 B
    float* zbuf     = (float*)(ws + 1270272);                 // 4194304 B
    unsigned short* ktbuf = (unsigned short*)(ws + 5464576);  // 33554432 B

    wprep_kernel<<<dim3(49), dim3(256), 0, stream>>>(
        Wq, Wkv, Wproj, scale, whi, wlo, sps);
    kproj_kernel<<<dim3(1024), dim3(256), 0, stream>>>(
        x, whi, wlo, sps, pos_enc, ktbuf, partial2);
    reducek_kernel<<<dim3(8), dim3(256), 0, stream>>>(partial2, kbar);
    qproj_kernel<<<dim3(1024), dim3(256), 0, stream>>>(
        x, whi, wlo, w_g, sps, kbar, zbuf, partial1);
    reduceg_kernel<<<dim3(8), dim3(256), 0, stream>>>(partial1, G);
    scp_kernel<<<dim3(1024), dim3(256), 0, stream>>>(
        out, ktbuf, zbuf, G, whi, wlo, bproj, dwc_w, dwc_b);
}

// Round 23
// 168.887 us; speedup vs baseline: 1.1149x; 1.1149x over previous
//
#include <hip/hip_runtime.h>
#include <hip/hip_bf16.h>

#define BB 8
#define NN 16384
#define CC 128

typedef __attribute__((ext_vector_type(8))) short bf16x8;
typedef __attribute__((ext_vector_type(4))) short short4v;
typedef __attribute__((ext_vector_type(4))) float f32x4;

__device__ __forceinline__ unsigned short f2bf(float f) {
    union { float f; unsigned u; } v; v.f = f;
    unsigned r = v.u + 0x7fffu + ((v.u >> 16) & 1u);
    return (unsigned short)(r >> 16);
}
__device__ __forceinline__ float bf2f(unsigned short h) {
    union { unsigned u; float f; } v; v.u = ((unsigned)h) << 16;
    return v.f;
}
// truncating hi/lo split: lo captures the residual, RNE on hi unnecessary
__device__ __forceinline__ void split_trunc(float f, short& hi, short& lo) {
    union { float f; unsigned u; } v; v.f = f;
    const unsigned short hu = (unsigned short)(v.u >> 16);
    union { unsigned u; float f; } hf; hf.u = ((unsigned)hu) << 16;
    union { float f; unsigned u; } r; r.f = f - hf.f;
    hi = (short)hu;
    lo = (short)(r.u >> 16);
}

// ---------------------------------------------------------------------------
// W prep: split Wq/Wkv/Wproj into bf16 hi/lo (blocks 0-47); block 48
// precomputes sps[c] = 1/softplus(scale[c]). grid 49, block 256.
// ---------------------------------------------------------------------------
__global__ __launch_bounds__(256) void wprep_kernel(
    const float* __restrict__ Wq, const float* __restrict__ Wkv,
    const float* __restrict__ Wp, const float* __restrict__ scale,
    unsigned short* __restrict__ whi, unsigned short* __restrict__ wlo,
    float* __restrict__ sps)
{
    const int bid = blockIdx.x;
    if (bid == 48) {
        if (threadIdx.x < 128)
            sps[threadIdx.x] = 1.f / log1pf(expf(scale[threadIdx.x]));
        return;
    }
    const int mat = bid >> 4;
    const float* src = (mat == 0) ? Wq : ((mat == 1) ? Wkv : Wp);
    const int off = (bid & 15) * 1024 + threadIdx.x * 4;
    const float4 v = *(const float4*)(src + off);
    float f[4] = {v.x, v.y, v.z, v.w};
    short4v hv, lv;
#pragma unroll
    for (int j = 0; j < 4; ++j) {
        short h, lo2;
        split_trunc(f[j], h, lo2);
        hv[j] = h; lv[j] = lo2;
    }
    *(short4v*)(whi + mat * 16384 + off) = hv;
    *(short4v*)(wlo + mat * 16384 + off) = lv;
}

// ---------------------------------------------------------------------------
// kproj: x @ Wkv.T + pos + focusing -> k_t + ksum. Runs FIRST so kbar is
// ready before qproj. grid 1024, block 256.
// ---------------------------------------------------------------------------
__global__ __launch_bounds__(256, 2) void kproj_kernel(
    const float* __restrict__ x, const unsigned short* __restrict__ whi,
    const unsigned short* __restrict__ wlo,
    const float* __restrict__ sps, const float* __restrict__ pos_enc,
    unsigned short* __restrict__ ktout, float* __restrict__ partial2)
{
    __shared__ __align__(16) char wsm[65536];
    __shared__ float wpart[4][128];

    const int tid  = threadIdx.x;
    const int w    = tid >> 6;
    const int l    = tid & 63;
    const int blk  = blockIdx.x;
    const int tok0 = blk * 128;
    const int tokb = (blk & 127) * 128;

    bf16x8 xh[2][4], xl[2][4];
#pragma unroll
    for (int n = 0; n < 2; ++n) {
        const int r = w * 32 + n * 16 + (l & 15);
        const float* rowp = x + (tok0 + r) * 128 + (l >> 4) * 8;
#pragma unroll
        for (int kt = 0; kt < 4; ++kt) {
            const f32x4 a = *(const f32x4*)(rowp + kt * 32);
            const f32x4 b = *(const f32x4*)(rowp + kt * 32 + 4);
            const float f[8] = {a[0], a[1], a[2], a[3], b[0], b[1], b[2], b[3]};
            bf16x8 hv, lv;
#pragma unroll
            for (int j = 0; j < 8; ++j) {
                short h, lo2;
                split_trunc(f[j], h, lo2);
                hv[j] = h; lv[j] = lo2;
            }
            xh[n][kt] = hv; xl[n][kt] = lv;
        }
    }

#pragma unroll
    for (int it = 0; it < 16; ++it) {
        const int flat = it * 256 + tid;
        const int arr  = flat >> 11;
        const int c    = (flat >> 4) & 127;
        const int g    = flat & 15;
        const unsigned short* src = (arr ? wlo : whi) + 16384 + c * 128 + g * 8;
        const int dst = arr * 32768 + c * 256 + ((g * 16) ^ ((c & 7) << 4));
        *(bf16x8*)(wsm + dst) = *(const bf16x8*)src;
    }
    __syncthreads();

    const int crow = (l >> 4) * 4;
    f32x4 acc[8][2];
#pragma unroll
    for (int m = 0; m < 8; ++m)
#pragma unroll
        for (int n = 0; n < 2; ++n) acc[m][n] = (f32x4)0.f;

#pragma unroll
    for (int m = 0; m < 8; ++m) {
        const int c = m * 16 + (l & 15);
        const int sw = (c & 7) << 4;
        bf16x8 ah[4], al[4];
#pragma unroll
        for (int kt = 0; kt < 4; ++kt) {
            const int fo = c * 256 + ((kt * 64 + (l >> 4) * 16) ^ sw);
            ah[kt] = *(const bf16x8*)(wsm + fo);
            al[kt] = *(const bf16x8*)(wsm + 32768 + fo);
        }
#pragma unroll
        for (int n = 0; n < 2; ++n)
#pragma unroll
            for (int kt = 0; kt < 4; ++kt) {
                acc[m][n] = __builtin_amdgcn_mfma_f32_16x16x32_bf16(ah[kt], xh[n][kt], acc[m][n], 0, 0, 0);
                acc[m][n] = __builtin_amdgcn_mfma_f32_16x16x32_bf16(ah[kt], xl[n][kt], acc[m][n], 0, 0, 0);
                acc[m][n] = __builtin_amdgcn_mfma_f32_16x16x32_bf16(al[kt], xh[n][kt], acc[m][n], 0, 0, 0);
            }
    }
    __syncthreads();

#pragma unroll
    for (int m = 0; m < 8; ++m) {
        const float4 is4 = *(const float4*)(sps + m * 16 + crow);
        const float is[4] = {is4.x, is4.y, is4.z, is4.w};
#pragma unroll
        for (int n = 0; n < 2; ++n) {
            const int t = tokb + w * 32 + n * 16 + (l & 15);
            const float4 p = *(const float4*)(pos_enc + t * 128 + m * 16 + crow);
            const float pe[4] = {p.x, p.y, p.z, p.w};
#pragma unroll
            for (int j = 0; j < 4; ++j)
                acc[m][n][j] = (fmaxf(acc[m][n][j] + pe[j], 0.f) + 1e-6f) * is[j];
        }
    }
    float fkn[2];
#pragma unroll
    for (int n = 0; n < 2; ++n) {
        float s2 = 0.f, s6 = 0.f;
#pragma unroll
        for (int m = 0; m < 8; ++m)
#pragma unroll
            for (int j = 0; j < 4; ++j) {
                const float v = acc[m][n][j], v2 = v * v;
                s2 += v2; s6 += v2 * v2 * v2;
            }
        s2 += __shfl_xor(s2, 16); s6 += __shfl_xor(s6, 16);
        s2 += __shfl_xor(s2, 32); s6 += __shfl_xor(s6, 32);
        fkn[n] = sqrtf(s2 / s6);
    }
#pragma unroll
    for (int m = 0; m < 8; ++m)
#pragma unroll
        for (int n = 0; n < 2; ++n)
#pragma unroll
            for (int j = 0; j < 4; ++j) {
                const float v = acc[m][n][j];
                acc[m][n][j] = v * v * v * fkn[n];
            }
#pragma unroll
    for (int m = 0; m < 8; ++m)
#pragma unroll
        for (int j = 0; j < 4; ++j) {
            float s = acc[m][0][j] + acc[m][1][j];
            s += __shfl_xor(s, 1); s += __shfl_xor(s, 2);
            s += __shfl_xor(s, 4); s += __shfl_xor(s, 8);
            if ((l & 15) == 0) wpart[w][m * 16 + crow + j] = s;
        }

#pragma unroll
    for (int m = 0; m < 8; ++m)
#pragma unroll
        for (int n = 0; n < 2; ++n)
#pragma unroll
            for (int j = 0; j < 4; ++j) {
                const int ch = m * 16 + crow + j;
                const int tl = w * 32 + n * 16 + (l & 15);
                *(unsigned short*)(wsm + ch * 264 + tl * 2) = f2bf(acc[m][n][j]);
            }
    __syncthreads();
    {
        const int bb = blk >> 7;
        unsigned* ktp = (unsigned*)ktout;
#pragma unroll
        for (int it = 0; it < 32; ++it) {
            const int idx = it * 256 + tid;
            const int row = idx >> 6;
            const int col = idx & 63;
            const unsigned v = *(unsigned*)(wsm + row * 264 + col * 4);
            ktp[(size_t)(bb * 128 + row) * 8192 + (blk & 127) * 64 + col] = v;
        }
    }
    __syncthreads();
    if (tid < 128)
        partial2[blk * 128 + tid] = wpart[0][tid] + wpart[1][tid] +
                                    wpart[2][tid] + wpart[3][tid];
}

// ---------------------------------------------------------------------------
// reduce_k: kbar from kproj partials. grid 8, block 256.
// ---------------------------------------------------------------------------
__global__ __launch_bounds__(256) void reducek_kernel(
    const float* __restrict__ partial2, float* __restrict__ kbar)
{
    const int b = blockIdx.x;
    const int tid = threadIdx.x;
    if (tid < 128) {
        float s = 0.f;
        for (int t = 0; t < 128; ++t)
            s += partial2[(b * 128 + t) * 128 + tid];
        kbar[b * 128 + tid] = s * (1.f / 16384.f);
    }
}

// ---------------------------------------------------------------------------
// qproj v2: x @ Wq.T + focusing; z inline from fp32 accs; G partials via
// shuffle algebra. grid 1024, block 256.
// ---------------------------------------------------------------------------
__global__ __launch_bounds__(256, 2) void qproj_kernel(
    const float* __restrict__ x, const unsigned short* __restrict__ whi,
    const unsigned short* __restrict__ wlo, const float* __restrict__ w_g,
    const float* __restrict__ sps, const float* __restrict__ kbar,
    float* __restrict__ z, float* __restrict__ partial1)
{
    __shared__ __align__(16) char wsm[65536];
    __shared__ float wpart[4][132];

    const int tid  = threadIdx.x;
    const int w    = tid >> 6;
    const int l    = tid & 63;
    const int blk  = blockIdx.x;
    const int tok0 = blk * 128;
    const int bq   = blk >> 7;
    const int tokb = (blk & 127) * 128;

    bf16x8 xh[2][4], xl[2][4];
#pragma unroll
    for (int n = 0; n < 2; ++n) {
        const int r = w * 32 + n * 16 + (l & 15);
        const float* rowp = x + (tok0 + r) * 128 + (l >> 4) * 8;
#pragma unroll
        for (int kt = 0; kt < 4; ++kt) {
            const f32x4 a = *(const f32x4*)(rowp + kt * 32);
            const f32x4 b = *(const f32x4*)(rowp + kt * 32 + 4);
            const float f[8] = {a[0], a[1], a[2], a[3], b[0], b[1], b[2], b[3]};
            bf16x8 hv, lv;
#pragma unroll
            for (int j = 0; j < 8; ++j) {
                short h, lo2;
                split_trunc(f[j], h, lo2);
                hv[j] = h; lv[j] = lo2;
            }
            xh[n][kt] = hv; xl[n][kt] = lv;
        }
    }

#pragma unroll
    for (int it = 0; it < 16; ++it) {
        const int flat = it * 256 + tid;
        const int arr  = flat >> 11;
        const int c    = (flat >> 4) & 127;
        const int g    = flat & 15;
        const unsigned short* src = (arr ? wlo : whi) + c * 128 + g * 8;
        const int dst = arr * 32768 + c * 256 + ((g * 16) ^ ((c & 7) << 4));
        *(bf16x8*)(wsm + dst) = *(const bf16x8*)src;
    }
    __syncthreads();

    const int crow = (l >> 4) * 4;
    f32x4 acc[8][2];
#pragma unroll
    for (int m = 0; m < 8; ++m)
#pragma unroll
        for (int n = 0; n < 2; ++n) acc[m][n] = (f32x4)0.f;

#pragma unroll
    for (int m = 0; m < 8; ++m) {
        const int c = m * 16 + (l & 15);
        const int sw = (c & 7) << 4;
        bf16x8 ah[4], al[4];
#pragma unroll
        for (int kt = 0; kt < 4; ++kt) {
            const int fo = c * 256 + ((kt * 64 + (l >> 4) * 16) ^ sw);
            ah[kt] = *(const bf16x8*)(wsm + fo);
            al[kt] = *(const bf16x8*)(wsm + 32768 + fo);
        }
#pragma unroll
        for (int n = 0; n < 2; ++n)
#pragma unroll
            for (int kt = 0; kt < 4; ++kt) {
                acc[m][n] = __builtin_amdgcn_mfma_f32_16x16x32_bf16(ah[kt], xh[n][kt], acc[m][n], 0, 0, 0);
                acc[m][n] = __builtin_amdgcn_mfma_f32_16x16x32_bf16(ah[kt], xl[n][kt], acc[m][n], 0, 0, 0);
                acc[m][n] = __builtin_amdgcn_mfma_f32_16x16x32_bf16(al[kt], xh[n][kt], acc[m][n], 0, 0, 0);
            }
    }

#pragma unroll
    for (int m = 0; m < 8; ++m) {
        const float4 is4 = *(const float4*)(sps + m * 16 + crow);
        const float is[4] = {is4.x, is4.y, is4.z, is4.w};
#pragma unroll
        for (int n = 0; n < 2; ++n)
#pragma unroll
            for (int j = 0; j < 4; ++j)
                acc[m][n][j] = (fmaxf(acc[m][n][j], 0.f) + 1e-6f) * is[j];
    }
    float fqn[2];
#pragma unroll
    for (int n = 0; n < 2; ++n) {
        float s2 = 0.f, s6 = 0.f;
#pragma unroll
        for (int m = 0; m < 8; ++m)
#pragma unroll
            for (int j = 0; j < 4; ++j) {
                const float v = acc[m][n][j], v2 = v * v;
                s2 += v2; s6 += v2 * v2 * v2;
            }
        s2 += __shfl_xor(s2, 16); s6 += __shfl_xor(s6, 16);
        s2 += __shfl_xor(s2, 32); s6 += __shfl_xor(s6, 32);
        fqn[n] = sqrtf(s2 / s6);
    }
#pragma unroll
    for (int m = 0; m < 8; ++m)
#pragma unroll
        for (int n = 0; n < 2; ++n)
#pragma unroll
            for (int j = 0; j < 4; ++j) {
                const float v = acc[m][n][j];
                acc[m][n][j] = v * v * v * fqn[n];
            }

#pragma unroll
    for (int m = 0; m < 8; ++m) {
        const float4 kb = *(const float4*)(kbar + bq * 128 + m * 16 + crow);
        const float kbv[4] = {kb.x, kb.y, kb.z, kb.w};
        float dm0 = 0.f, dm1 = 0.f;
#pragma unroll
        for (int j = 0; j < 4; ++j) {
            dm0 += acc[m][0][j] * kbv[j];
            dm1 += acc[m][1][j] * kbv[j];
        }
        dm0 += __shfl_xor(dm0, 16); dm0 += __shfl_xor(dm0, 32);
        dm1 += __shfl_xor(dm1, 16); dm1 += __shfl_xor(dm1, 32);
        if (l < 16) {
            const int t0 = tokb + w * 32 + l;
            z[((size_t)bq * 8 + m) * NN + t0]      = 1.f / (dm0 + 1e-6f);
            z[((size_t)bq * 8 + m) * NN + t0 + 16] = 1.f / (dm1 + 1e-6f);
        }
    }

    float d0 = 0.f, d1 = 0.f;
#pragma unroll
    for (int m = 0; m < 8; ++m) {
        const float4 wgv = *(const float4*)(w_g + m * 16 + crow);
#pragma unroll
        for (int j = 0; j < 4; ++j) {
            const float wg = (j == 0) ? wgv.x : (j == 1) ? wgv.y : (j == 2) ? wgv.z : wgv.w;
            d0 += acc[m][0][j] * wg;
            d1 += acc[m][1][j] * wg;
        }
    }
    d0 += __shfl_xor(d0, 16); d0 += __shfl_xor(d0, 32);
    d1 += __shfl_xor(d1, 16); d1 += __shfl_xor(d1, 32);
    const float ap0 = 0.25f * d0, ap1 = 0.25f * d1;

    float ssa = ap0 * ap0 + ap1 * ap1;
    ssa += __shfl_xor(ssa, 1); ssa += __shfl_xor(ssa, 2);
    ssa += __shfl_xor(ssa, 4); ssa += __shfl_xor(ssa, 8);
    if (l == 0) wpart[w][128] = ssa;

#pragma unroll
    for (int m = 0; m < 8; ++m)
#pragma unroll
        for (int j = 0; j < 4; ++j) {
            float g = ap0 * acc[m][0][j] + ap1 * acc[m][1][j];
            g += __shfl_xor(g, 1); g += __shfl_xor(g, 2);
            g += __shfl_xor(g, 4); g += __shfl_xor(g, 8);
            if ((l & 15) == 0) wpart[w][m * 16 + crow + j] = g;
        }
    __syncthreads();
    float* pblk = partial1 + blk * 132;
    if (tid < 128)
        pblk[tid] = wpart[0][tid] + wpart[1][tid] + wpart[2][tid] + wpart[3][tid];
    else if (tid == 128)
        pblk[128] = wpart[0][128] + wpart[1][128] + wpart[2][128] + wpart[3][128];
}

// ---------------------------------------------------------------------------
// reduce_g: G from qproj partials (+ssa normalization). grid 8, block 256.
// ---------------------------------------------------------------------------
__global__ __launch_bounds__(256) void reduceg_kernel(
    const float* __restrict__ partial1, float* __restrict__ G)
{
    const int b = blockIdx.x;
    const int tid = threadIdx.x;
    __shared__ float tmp[4];

    float ssa = (tid < 128) ? partial1[(b * 128 + tid) * 132 + 128] : 0.f;
#pragma unroll
    for (int o = 32; o >= 1; o >>= 1) ssa += __shfl_xor(ssa, o);
    if ((tid & 63) == 0) tmp[tid >> 6] = ssa;
    __syncthreads();
    const float anorm = fmaxf(sqrtf(tmp[0] + tmp[1] + tmp[2] + tmp[3]), 1e-12f);
    const float inv_a = 1.f / anorm;

    if (tid < 128) {
        float g = 0.f;
        for (int t = 0; t < 128; ++t)
            g += partial1[(b * 128 + t) * 132 + tid];
        G[b * 128 + tid] = g * inv_a;
    }
}

// ---------------------------------------------------------------------------
// scp (R21 exact — best measured 79.5us): channel-major conv with scattered
// global reads + u-part inline + proj MFMA, swz(r)=((r&7)^((r>>3)&7))<<4.
// R22's LDS-staged variant regressed (16-way conflicts from 264B-pitch x
// 4ch-stride consume + 10 barriers at 2 blocks/CU). grid 1024, block 256.
// NOTE: conv halo under-reads 16B before ktbuf row 0 — ktbuf must NOT sit
// at d_ws offset 0 (R20's crash).
// ---------------------------------------------------------------------------
__global__ __launch_bounds__(256, 2) void scp_kernel(
    float* __restrict__ out, const unsigned short* __restrict__ kt,
    const float* __restrict__ z, const float* __restrict__ G,
    const unsigned short* __restrict__ whi, const unsigned short* __restrict__ wlo,
    const float* __restrict__ bp, const float* __restrict__ dwc_w,
    const float* __restrict__ dwc_b)
{
    __shared__ __align__(16) char smem[32768];
    __shared__ float wct[25][16];
    __shared__ float bi[16];
    __shared__ float Gs;

    const int tid  = threadIdx.x;
    const int bid0 = blockIdx.x;
    const int bid  = (bid0 & 7) * 128 + (bid0 >> 3);
    const int cc   = bid & 127;
    const int b    = bid >> 7;
    const int n0   = bid * 128;

    for (int i = tid; i < 400; i += 256)
        wct[i >> 4][i & 15] = dwc_w[(i & 15) * 25 + (i >> 4)];
    if (tid < 16) bi[tid] = dwc_b[tid];
    if (tid == 0) Gs = G[b * 128 + cc];
    __syncthreads();

    const int ch4 = tid >> 3;
    const int xg  = tid & 7;

    float acc[4][16];
#pragma unroll
    for (int c = 0; c < 4; ++c)
#pragma unroll
        for (int i = 0; i < 16; ++i) acc[c][i] = 0.f;

#pragma unroll
    for (int dy = 0; dy < 5; ++dy) {
        const int yy = cc + dy - 2;
        if (yy < 0 || yy > 127) continue;
#pragma unroll
        for (int c = 0; c < 4; ++c) {
            const int ch = ch4 * 4 + c;
            const unsigned short* rowp = kt + ((size_t)b * 128 + ch) * NN
                                            + yy * 128 + xg * 16 - 8;
            float wf[32];
#pragma unroll
            for (int q4 = 0; q4 < 4; ++q4) {
                const bf16x8 v = *(const bf16x8*)(rowp + q4 * 8);
#pragma unroll
                for (int e = 0; e < 8; ++e)
                    wf[q4 * 8 + e] = bf2f((unsigned short)v[e]);
            }
            if (xg == 0) {
#pragma unroll
                for (int e = 0; e < 8; ++e) wf[e] = 0.f;
            }
            if (xg == 7) {
#pragma unroll
                for (int e = 24; e < 32; ++e) wf[e] = 0.f;
            }
            const int d = ch & 15;
#pragma unroll
            for (int dx = 0; dx < 5; ++dx) {
                const float wv = wct[dy * 5 + dx][d];
#pragma unroll
                for (int i = 0; i < 16; ++i)
                    acc[c][i] += wv * wf[i + dx + 6];
            }
        }
    }

    const float Gcc = Gs;
    const unsigned short* kub = kt + ((size_t)b * 128 + cc) * NN;
    const float* zr = z + ((size_t)b * 8 + (cc >> 4)) * NN;
    const int dbase = (ch4 & 3) * 4;
    const float4 b4 = *(const float4*)(&bi[dbase]);
    const float bv[4] = {b4.x, b4.y, b4.z, b4.w};
#pragma unroll
    for (int i = 0; i < 16; ++i) {
        const int r = xg * 16 + i;
        const int toks = r * 128 + ch4 * 4;
        const short4v ku4 = *(const short4v*)(kub + toks);
        const float4 z4 = *(const float4*)(zr + toks);
        const float zz[4] = {z4.x, z4.y, z4.z, z4.w};
        short4v hv;
#pragma unroll
        for (int c = 0; c < 4; ++c) {
            const float f = Gcc * bf2f((unsigned short)ku4[c]) * zz[c] + acc[c][i] + bv[c];
            hv[c] = (short)f2bf(f);
        }
        const int swz = (((r & 7) ^ ((r >> 3) & 7)) << 4);
        const int ad = r * 256 + (((ch4 >> 1) * 16) ^ swz) + (ch4 & 1) * 8;
        *(short4v*)(smem + ad) = hv;
    }
    __syncthreads();

    const int w  = tid >> 6;
    const int ll = tid & 63;
    bf16x8 xh[2][4];
    {
        const int lg16 = (ll >> 4) * 16;
#pragma unroll
        for (int n = 0; n < 2; ++n) {
            const int r = w * 32 + n * 16 + (ll & 15);
            const int rb = r * 256;
            const int swz = (((r & 7) ^ ((r >> 3) & 7)) << 4);
#pragma unroll
            for (int kt2 = 0; kt2 < 4; ++kt2)
                xh[n][kt2] = *(bf16x8*)(smem + rb + ((kt2 * 64 + lg16) ^ swz));
        }
    }
    const int crow = (ll >> 4) * 4;
    f32x4 pacc[8][2];
#pragma unroll
    for (int m = 0; m < 8; ++m)
#pragma unroll
        for (int n = 0; n < 2; ++n) pacc[m][n] = (f32x4)0.f;

#pragma unroll
    for (int m = 0; m < 8; ++m) {
        const int c = m * 16 + (ll & 15);
        bf16x8 ah[4], al[4];
#pragma unroll
        for (int kt2 = 0; kt2 < 4; ++kt2) {
            const int off = 32768 + c * 128 + kt2 * 32 + (ll >> 4) * 8;
            ah[kt2] = *(const bf16x8*)(whi + off);
            al[kt2] = *(const bf16x8*)(wlo + off);
        }
#pragma unroll
        for (int n = 0; n < 2; ++n)
#pragma unroll
            for (int kt2 = 0; kt2 < 4; ++kt2) {
                pacc[m][n] = __builtin_amdgcn_mfma_f32_16x16x32_bf16(ah[kt2], xh[n][kt2], pacc[m][n], 0, 0, 0);
                pacc[m][n] = __builtin_amdgcn_mfma_f32_16x16x32_bf16(al[kt2], xh[n][kt2], pacc[m][n], 0, 0, 0);
            }
    }

#pragma unroll
    for (int m = 0; m < 8; ++m) {
        const float4 bq = *(const float4*)(bp + m * 16 + crow);
        const float bb[4] = {bq.x, bq.y, bq.z, bq.w};
#pragma unroll
        for (int n = 0; n < 2; ++n)
#pragma unroll
            for (int j = 0; j < 4; ++j) pacc[m][n][j] += bb[j];
    }
    __syncthreads();
#pragma unroll
    for (int n = 0; n < 2; ++n) {
        const int t = ll & 15;
        const int rb = w * 8192 + t * 512;
#pragma unroll
        for (int m = 0; m < 8; ++m) {
            const int ad = rb + (((m * 16 + crow) * 4) ^ ((t & 7) << 4));
            *(f32x4*)(smem + ad) = pacc[m][n];
        }
        asm volatile("s_waitcnt lgkmcnt(0)" ::: "memory");
#pragma unroll
        for (int j = 0; j < 8; ++j) {
            const int fid = j * 64 + ll;
            const int row = fid >> 5;
            const int c4  = fid & 31;
            const int rb3 = w * 8192 + row * 512;
            const f32x4 v = *(f32x4*)(smem + rb3 + ((c4 * 16) ^ ((row & 7) << 4)));
            *(f32x4*)(out + (n0 + w * 32 + n * 16 + row) * 128 + c4 * 4) = v;
        }
    }
}

// ---------------------------------------------------------------------------
extern "C" void kernel_launch(void* const* d_in, const int* in_sizes, int n_in,
                              void* d_out, int out_size, void* d_ws, size_t ws_size,
                              hipStream_t stream)
{
    const float* x       = (const float*)d_in[0];
    const float* Wq      = (const float*)d_in[1];
    const float* Wkv     = (const float*)d_in[2];
    const float* Wproj   = (const float*)d_in[3];
    const float* bproj   = (const float*)d_in[4];
    const float* w_g     = (const float*)d_in[5];
    const float* scale   = (const float*)d_in[6];
    const float* pos_enc = (const float*)d_in[7];
    const float* dwc_w   = (const float*)d_in[8];
    const float* dwc_b   = (const float*)d_in[9];
    float* out = (float*)d_out;

    // ktbuf deliberately NOT at offset 0 (scp conv halo under-reads 16B).
    char* ws = (char*)d_ws;
    float* partial1 = (float*)(ws);                           // 540672 B
    float* partial2 = (float*)(ws + 540672);                  // 524288 B
    float* G        = (float*)(ws + 1064960);                 // 4096 B
    float* kbar     = (float*)(ws + 1069056);                 // 4096 B
    unsigned short* whi = (unsigned short*)(ws + 1073152);    // 98304 B
    unsigned short* wlo = (unsigned short*)(ws + 1171456);    // 98304 B
    float* sps      = (float*)(ws + 1269760);                 // 512 B
    float* zbuf     = (float*)(ws + 1270272);                 // 4194304 B
    unsigned short* ktbuf = (unsigned short*)(ws + 5464576);  // 33554432 B

    wprep_kernel<<<dim3(49), dim3(256), 0, stream>>>(
        Wq, Wkv, Wproj, scale, whi, wlo, sps);
    kproj_kernel<<<dim3(1024), dim3(256), 0, stream>>>(
        x, whi, wlo, sps, pos_enc, ktbuf, partial2);
    reducek_kernel<<<dim3(8), dim3(256), 0, stream>>>(partial2, kbar);
    qproj_kernel<<<dim3(1024), dim3(256), 0, stream>>>(
        x, whi, wlo, w_g, sps, kbar, zbuf, partial1);
    reduceg_kernel<<<dim3(8), dim3(256), 0, stream>>>(partial1, G);
    scp_kernel<<<dim3(1024), dim3(256), 0, stream>>>(
        out, ktbuf, zbuf, G, whi, wlo, bproj, dwc_w, dwc_b);
}

// Round 24
// 162.438 us; speedup vs baseline: 1.1592x; 1.0397x over previous
//
#include <hip/hip_runtime.h>
#include <hip/hip_bf16.h>

#define BB 8
#define NN 16384
#define CC 128

typedef __attribute__((ext_vector_type(8))) short bf16x8;
typedef __attribute__((ext_vector_type(4))) short short4v;
typedef __attribute__((ext_vector_type(4))) float f32x4;

__device__ __forceinline__ unsigned short f2bf(float f) {
    union { float f; unsigned u; } v; v.f = f;
    unsigned r = v.u + 0x7fffu + ((v.u >> 16) & 1u);
    return (unsigned short)(r >> 16);
}
__device__ __forceinline__ float bf2f(unsigned short h) {
    union { unsigned u; float f; } v; v.u = ((unsigned)h) << 16;
    return v.f;
}
// truncating hi/lo split: lo captures the residual, RNE on hi unnecessary
__device__ __forceinline__ void split_trunc(float f, short& hi, short& lo) {
    union { float f; unsigned u; } v; v.f = f;
    const unsigned short hu = (unsigned short)(v.u >> 16);
    union { unsigned u; float f; } hf; hf.u = ((unsigned)hu) << 16;
    union { float f; unsigned u; } r; r.f = f - hf.f;
    hi = (short)hu;
    lo = (short)(r.u >> 16);
}

// ---------------------------------------------------------------------------
// W prep: split Wq/Wkv/Wproj into bf16 hi/lo (blocks 0-47); block 48
// precomputes sps[c] = 1/softplus(scale[c]). grid 49, block 256.
// ---------------------------------------------------------------------------
__global__ __launch_bounds__(256) void wprep_kernel(
    const float* __restrict__ Wq, const float* __restrict__ Wkv,
    const float* __restrict__ Wp, const float* __restrict__ scale,
    unsigned short* __restrict__ whi, unsigned short* __restrict__ wlo,
    float* __restrict__ sps)
{
    const int bid = blockIdx.x;
    if (bid == 48) {
        if (threadIdx.x < 128)
            sps[threadIdx.x] = 1.f / log1pf(expf(scale[threadIdx.x]));
        return;
    }
    const int mat = bid >> 4;
    const float* src = (mat == 0) ? Wq : ((mat == 1) ? Wkv : Wp);
    const int off = (bid & 15) * 1024 + threadIdx.x * 4;
    const float4 v = *(const float4*)(src + off);
    float f[4] = {v.x, v.y, v.z, v.w};
    short4v hv, lv;
#pragma unroll
    for (int j = 0; j < 4; ++j) {
        short h, lo2;
        split_trunc(f[j], h, lo2);
        hv[j] = h; lv[j] = lo2;
    }
    *(short4v*)(whi + mat * 16384 + off) = hv;
    *(short4v*)(wlo + mat * 16384 + off) = lv;
}

// ---------------------------------------------------------------------------
// kproj: x @ Wkv.T + pos + focusing -> k_t + ksum. Runs FIRST so kbar is
// ready before qproj. grid 1024, block 256.
// ---------------------------------------------------------------------------
__global__ __launch_bounds__(256, 2) void kproj_kernel(
    const float* __restrict__ x, const unsigned short* __restrict__ whi,
    const unsigned short* __restrict__ wlo,
    const float* __restrict__ sps, const float* __restrict__ pos_enc,
    unsigned short* __restrict__ ktout, float* __restrict__ partial2)
{
    __shared__ __align__(16) char wsm[65536];
    __shared__ float wpart[4][128];

    const int tid  = threadIdx.x;
    const int w    = tid >> 6;
    const int l    = tid & 63;
    const int blk  = blockIdx.x;
    const int tok0 = blk * 128;
    const int tokb = (blk & 127) * 128;

    bf16x8 xh[2][4], xl[2][4];
#pragma unroll
    for (int n = 0; n < 2; ++n) {
        const int r = w * 32 + n * 16 + (l & 15);
        const float* rowp = x + (tok0 + r) * 128 + (l >> 4) * 8;
#pragma unroll
        for (int kt = 0; kt < 4; ++kt) {
            const f32x4 a = *(const f32x4*)(rowp + kt * 32);
            const f32x4 b = *(const f32x4*)(rowp + kt * 32 + 4);
            const float f[8] = {a[0], a[1], a[2], a[3], b[0], b[1], b[2], b[3]};
            bf16x8 hv, lv;
#pragma unroll
            for (int j = 0; j < 8; ++j) {
                short h, lo2;
                split_trunc(f[j], h, lo2);
                hv[j] = h; lv[j] = lo2;
            }
            xh[n][kt] = hv; xl[n][kt] = lv;
        }
    }

#pragma unroll
    for (int it = 0; it < 16; ++it) {
        const int flat = it * 256 + tid;
        const int arr  = flat >> 11;
        const int c    = (flat >> 4) & 127;
        const int g    = flat & 15;
        const unsigned short* src = (arr ? wlo : whi) + 16384 + c * 128 + g * 8;
        const int dst = arr * 32768 + c * 256 + ((g * 16) ^ ((c & 7) << 4));
        *(bf16x8*)(wsm + dst) = *(const bf16x8*)src;
    }
    __syncthreads();

    const int crow = (l >> 4) * 4;
    f32x4 acc[8][2];
#pragma unroll
    for (int m = 0; m < 8; ++m)
#pragma unroll
        for (int n = 0; n < 2; ++n) acc[m][n] = (f32x4)0.f;

#pragma unroll
    for (int m = 0; m < 8; ++m) {
        const int c = m * 16 + (l & 15);
        const int sw = (c & 7) << 4;
        bf16x8 ah[4], al[4];
#pragma unroll
        for (int kt = 0; kt < 4; ++kt) {
            const int fo = c * 256 + ((kt * 64 + (l >> 4) * 16) ^ sw);
            ah[kt] = *(const bf16x8*)(wsm + fo);
            al[kt] = *(const bf16x8*)(wsm + 32768 + fo);
        }
#pragma unroll
        for (int n = 0; n < 2; ++n)
#pragma unroll
            for (int kt = 0; kt < 4; ++kt) {
                acc[m][n] = __builtin_amdgcn_mfma_f32_16x16x32_bf16(ah[kt], xh[n][kt], acc[m][n], 0, 0, 0);
                acc[m][n] = __builtin_amdgcn_mfma_f32_16x16x32_bf16(ah[kt], xl[n][kt], acc[m][n], 0, 0, 0);
                acc[m][n] = __builtin_amdgcn_mfma_f32_16x16x32_bf16(al[kt], xh[n][kt], acc[m][n], 0, 0, 0);
            }
    }
    __syncthreads();

#pragma unroll
    for (int m = 0; m < 8; ++m) {
        const float4 is4 = *(const float4*)(sps + m * 16 + crow);
        const float is[4] = {is4.x, is4.y, is4.z, is4.w};
#pragma unroll
        for (int n = 0; n < 2; ++n) {
            const int t = tokb + w * 32 + n * 16 + (l & 15);
            const float4 p = *(const float4*)(pos_enc + t * 128 + m * 16 + crow);
            const float pe[4] = {p.x, p.y, p.z, p.w};
#pragma unroll
            for (int j = 0; j < 4; ++j)
                acc[m][n][j] = (fmaxf(acc[m][n][j] + pe[j], 0.f) + 1e-6f) * is[j];
        }
    }
    float fkn[2];
#pragma unroll
    for (int n = 0; n < 2; ++n) {
        float s2 = 0.f, s6 = 0.f;
#pragma unroll
        for (int m = 0; m < 8; ++m)
#pragma unroll
            for (int j = 0; j < 4; ++j) {
                const float v = acc[m][n][j], v2 = v * v;
                s2 += v2; s6 += v2 * v2 * v2;
            }
        s2 += __shfl_xor(s2, 16); s6 += __shfl_xor(s6, 16);
        s2 += __shfl_xor(s2, 32); s6 += __shfl_xor(s6, 32);
        fkn[n] = sqrtf(s2 / s6);
    }
#pragma unroll
    for (int m = 0; m < 8; ++m)
#pragma unroll
        for (int n = 0; n < 2; ++n)
#pragma unroll
            for (int j = 0; j < 4; ++j) {
                const float v = acc[m][n][j];
                acc[m][n][j] = v * v * v * fkn[n];
            }
#pragma unroll
    for (int m = 0; m < 8; ++m)
#pragma unroll
        for (int j = 0; j < 4; ++j) {
            float s = acc[m][0][j] + acc[m][1][j];
            s += __shfl_xor(s, 1); s += __shfl_xor(s, 2);
            s += __shfl_xor(s, 4); s += __shfl_xor(s, 8);
            if ((l & 15) == 0) wpart[w][m * 16 + crow + j] = s;
        }

#pragma unroll
    for (int m = 0; m < 8; ++m)
#pragma unroll
        for (int n = 0; n < 2; ++n)
#pragma unroll
            for (int j = 0; j < 4; ++j) {
                const int ch = m * 16 + crow + j;
                const int tl = w * 32 + n * 16 + (l & 15);
                *(unsigned short*)(wsm + ch * 264 + tl * 2) = f2bf(acc[m][n][j]);
            }
    __syncthreads();
    {
        const int bb = blk >> 7;
        unsigned* ktp = (unsigned*)ktout;
#pragma unroll
        for (int it = 0; it < 32; ++it) {
            const int idx = it * 256 + tid;
            const int row = idx >> 6;
            const int col = idx & 63;
            const unsigned v = *(unsigned*)(wsm + row * 264 + col * 4);
            ktp[(size_t)(bb * 128 + row) * 8192 + (blk & 127) * 64 + col] = v;
        }
    }
    __syncthreads();
    if (tid < 128)
        partial2[blk * 128 + tid] = wpart[0][tid] + wpart[1][tid] +
                                    wpart[2][tid] + wpart[3][tid];
}

// ---------------------------------------------------------------------------
// reduce_k v2: kbar from kproj partials. R23 ran 8 blocks x 128 active
// threads with a 128-iteration serial loop (3% of chip, long chain).
// Now block=1024 (16 waves): 8 slices x 128 channels, 16-iter loops,
// LDS tree combine. grid 8.
// ---------------------------------------------------------------------------
__global__ __launch_bounds__(1024) void reducek_kernel(
    const float* __restrict__ partial2, float* __restrict__ kbar)
{
    __shared__ float sl[8][128];
    const int b   = blockIdx.x;
    const int tid = threadIdx.x;
    const int c   = tid & 127;
    const int s   = tid >> 7;            // slice 0..7

    float sum = 0.f;
#pragma unroll
    for (int i = 0; i < 16; ++i)
        sum += partial2[(b * 128 + s * 16 + i) * 128 + c];
    sl[s][c] = sum;
    __syncthreads();
    if (tid < 128) {
        float tot = 0.f;
#pragma unroll
        for (int s2 = 0; s2 < 8; ++s2) tot += sl[s2][tid];
        kbar[b * 128 + tid] = tot * (1.f / 16384.f);
    }
}

// ---------------------------------------------------------------------------
// qproj v2: x @ Wq.T + focusing; z inline from fp32 accs; G partials via
// shuffle algebra. grid 1024, block 256.
// ---------------------------------------------------------------------------
__global__ __launch_bounds__(256, 2) void qproj_kernel(
    const float* __restrict__ x, const unsigned short* __restrict__ whi,
    const unsigned short* __restrict__ wlo, const float* __restrict__ w_g,
    const float* __restrict__ sps, const float* __restrict__ kbar,
    float* __restrict__ z, float* __restrict__ partial1)
{
    __shared__ __align__(16) char wsm[65536];
    __shared__ float wpart[4][132];

    const int tid  = threadIdx.x;
    const int w    = tid >> 6;
    const int l    = tid & 63;
    const int blk  = blockIdx.x;
    const int tok0 = blk * 128;
    const int bq   = blk >> 7;
    const int tokb = (blk & 127) * 128;

    bf16x8 xh[2][4], xl[2][4];
#pragma unroll
    for (int n = 0; n < 2; ++n) {
        const int r = w * 32 + n * 16 + (l & 15);
        const float* rowp = x + (tok0 + r) * 128 + (l >> 4) * 8;
#pragma unroll
        for (int kt = 0; kt < 4; ++kt) {
            const f32x4 a = *(const f32x4*)(rowp + kt * 32);
            const f32x4 b = *(const f32x4*)(rowp + kt * 32 + 4);
            const float f[8] = {a[0], a[1], a[2], a[3], b[0], b[1], b[2], b[3]};
            bf16x8 hv, lv;
#pragma unroll
            for (int j = 0; j < 8; ++j) {
                short h, lo2;
                split_trunc(f[j], h, lo2);
                hv[j] = h; lv[j] = lo2;
            }
            xh[n][kt] = hv; xl[n][kt] = lv;
        }
    }

#pragma unroll
    for (int it = 0; it < 16; ++it) {
        const int flat = it * 256 + tid;
        const int arr  = flat >> 11;
        const int c    = (flat >> 4) & 127;
        const int g    = flat & 15;
        const unsigned short* src = (arr ? wlo : whi) + c * 128 + g * 8;
        const int dst = arr * 32768 + c * 256 + ((g * 16) ^ ((c & 7) << 4));
        *(bf16x8*)(wsm + dst) = *(const bf16x8*)src;
    }
    __syncthreads();

    const int crow = (l >> 4) * 4;
    f32x4 acc[8][2];
#pragma unroll
    for (int m = 0; m < 8; ++m)
#pragma unroll
        for (int n = 0; n < 2; ++n) acc[m][n] = (f32x4)0.f;

#pragma unroll
    for (int m = 0; m < 8; ++m) {
        const int c = m * 16 + (l & 15);
        const int sw = (c & 7) << 4;
        bf16x8 ah[4], al[4];
#pragma unroll
        for (int kt = 0; kt < 4; ++kt) {
            const int fo = c * 256 + ((kt * 64 + (l >> 4) * 16) ^ sw);
            ah[kt] = *(const bf16x8*)(wsm + fo);
            al[kt] = *(const bf16x8*)(wsm + 32768 + fo);
        }
#pragma unroll
        for (int n = 0; n < 2; ++n)
#pragma unroll
            for (int kt = 0; kt < 4; ++kt) {
                acc[m][n] = __builtin_amdgcn_mfma_f32_16x16x32_bf16(ah[kt], xh[n][kt], acc[m][n], 0, 0, 0);
                acc[m][n] = __builtin_amdgcn_mfma_f32_16x16x32_bf16(ah[kt], xl[n][kt], acc[m][n], 0, 0, 0);
                acc[m][n] = __builtin_amdgcn_mfma_f32_16x16x32_bf16(al[kt], xh[n][kt], acc[m][n], 0, 0, 0);
            }
    }

#pragma unroll
    for (int m = 0; m < 8; ++m) {
        const float4 is4 = *(const float4*)(sps + m * 16 + crow);
        const float is[4] = {is4.x, is4.y, is4.z, is4.w};
#pragma unroll
        for (int n = 0; n < 2; ++n)
#pragma unroll
            for (int j = 0; j < 4; ++j)
                acc[m][n][j] = (fmaxf(acc[m][n][j], 0.f) + 1e-6f) * is[j];
    }
    float fqn[2];
#pragma unroll
    for (int n = 0; n < 2; ++n) {
        float s2 = 0.f, s6 = 0.f;
#pragma unroll
        for (int m = 0; m < 8; ++m)
#pragma unroll
            for (int j = 0; j < 4; ++j) {
                const float v = acc[m][n][j], v2 = v * v;
                s2 += v2; s6 += v2 * v2 * v2;
            }
        s2 += __shfl_xor(s2, 16); s6 += __shfl_xor(s6, 16);
        s2 += __shfl_xor(s2, 32); s6 += __shfl_xor(s6, 32);
        fqn[n] = sqrtf(s2 / s6);
    }
#pragma unroll
    for (int m = 0; m < 8; ++m)
#pragma unroll
        for (int n = 0; n < 2; ++n)
#pragma unroll
            for (int j = 0; j < 4; ++j) {
                const float v = acc[m][n][j];
                acc[m][n][j] = v * v * v * fqn[n];
            }

#pragma unroll
    for (int m = 0; m < 8; ++m) {
        const float4 kb = *(const float4*)(kbar + bq * 128 + m * 16 + crow);
        const float kbv[4] = {kb.x, kb.y, kb.z, kb.w};
        float dm0 = 0.f, dm1 = 0.f;
#pragma unroll
        for (int j = 0; j < 4; ++j) {
            dm0 += acc[m][0][j] * kbv[j];
            dm1 += acc[m][1][j] * kbv[j];
        }
        dm0 += __shfl_xor(dm0, 16); dm0 += __shfl_xor(dm0, 32);
        dm1 += __shfl_xor(dm1, 16); dm1 += __shfl_xor(dm1, 32);
        if (l < 16) {
            const int t0 = tokb + w * 32 + l;
            z[((size_t)bq * 8 + m) * NN + t0]      = 1.f / (dm0 + 1e-6f);
            z[((size_t)bq * 8 + m) * NN + t0 + 16] = 1.f / (dm1 + 1e-6f);
        }
    }

    float d0 = 0.f, d1 = 0.f;
#pragma unroll
    for (int m = 0; m < 8; ++m) {
        const float4 wgv = *(const float4*)(w_g + m * 16 + crow);
#pragma unroll
        for (int j = 0; j < 4; ++j) {
            const float wg = (j == 0) ? wgv.x : (j == 1) ? wgv.y : (j == 2) ? wgv.z : wgv.w;
            d0 += acc[m][0][j] * wg;
            d1 += acc[m][1][j] * wg;
        }
    }
    d0 += __shfl_xor(d0, 16); d0 += __shfl_xor(d0, 32);
    d1 += __shfl_xor(d1, 16); d1 += __shfl_xor(d1, 32);
    const float ap0 = 0.25f * d0, ap1 = 0.25f * d1;

    float ssa = ap0 * ap0 + ap1 * ap1;
    ssa += __shfl_xor(ssa, 1); ssa += __shfl_xor(ssa, 2);
    ssa += __shfl_xor(ssa, 4); ssa += __shfl_xor(ssa, 8);
    if (l == 0) wpart[w][128] = ssa;

#pragma unroll
    for (int m = 0; m < 8; ++m)
#pragma unroll
        for (int j = 0; j < 4; ++j) {
            float g = ap0 * acc[m][0][j] + ap1 * acc[m][1][j];
            g += __shfl_xor(g, 1); g += __shfl_xor(g, 2);
            g += __shfl_xor(g, 4); g += __shfl_xor(g, 8);
            if ((l & 15) == 0) wpart[w][m * 16 + crow + j] = g;
        }
    __syncthreads();
    float* pblk = partial1 + blk * 132;
    if (tid < 128)
        pblk[tid] = wpart[0][tid] + wpart[1][tid] + wpart[2][tid] + wpart[3][tid];
    else if (tid == 128)
        pblk[128] = wpart[0][128] + wpart[1][128] + wpart[2][128] + wpart[3][128];
}

// ---------------------------------------------------------------------------
// reduce_g v2: G from qproj partials (+ssa norm). block=1024 (16 waves):
// 8 slices x 128 channels (16-iter loops) + 2-wave shuffle reduce for ssa
// running in parallel; LDS combine. grid 8.
// ---------------------------------------------------------------------------
__global__ __launch_bounds__(1024) void reduceg_kernel(
    const float* __restrict__ partial1, float* __restrict__ G)
{
    __shared__ float sl[8][128];
    __shared__ float ssl[2];
    __shared__ float inv_a_sh;
    const int b   = blockIdx.x;
    const int tid = threadIdx.x;
    const int c   = tid & 127;
    const int s   = tid >> 7;            // slice 0..7

    // per-slice channel sums (all 1024 threads)
    float sum = 0.f;
#pragma unroll
    for (int i = 0; i < 16; ++i)
        sum += partial1[(b * 128 + s * 16 + i) * 132 + c];
    sl[s][c] = sum;

    // ssa total (first 2 waves: one value per tile)
    if (tid < 128) {
        float ssa = partial1[(b * 128 + tid) * 132 + 128];
#pragma unroll
        for (int o = 32; o >= 1; o >>= 1) ssa += __shfl_xor(ssa, o);
        if ((tid & 63) == 0) ssl[tid >> 6] = ssa;
    }
    __syncthreads();
    if (tid == 0)
        inv_a_sh = 1.f / fmaxf(sqrtf(ssl[0] + ssl[1]), 1e-12f);
    __syncthreads();

    if (tid < 128) {
        float tot = 0.f;
#pragma unroll
        for (int s2 = 0; s2 < 8; ++s2) tot += sl[s2][tid];
        G[b * 128 + tid] = tot * inv_a_sh;
    }
}

// ---------------------------------------------------------------------------
// scp (R21 exact — best measured 79.5us): channel-major conv with scattered
// global reads + u-part inline + proj MFMA, swz(r)=((r&7)^((r>>3)&7))<<4.
// grid 1024, block 256. NOTE: conv halo under-reads 16B before ktbuf row 0
// — ktbuf must NOT sit at d_ws offset 0 (R20's crash).
// ---------------------------------------------------------------------------
__global__ __launch_bounds__(256, 2) void scp_kernel(
    float* __restrict__ out, const unsigned short* __restrict__ kt,
    const float* __restrict__ z, const float* __restrict__ G,
    const unsigned short* __restrict__ whi, const unsigned short* __restrict__ wlo,
    const float* __restrict__ bp, const float* __restrict__ dwc_w,
    const float* __restrict__ dwc_b)
{
    __shared__ __align__(16) char smem[32768];
    __shared__ float wct[25][16];
    __shared__ float bi[16];
    __shared__ float Gs;

    const int tid  = threadIdx.x;
    const int bid0 = blockIdx.x;
    const int bid  = (bid0 & 7) * 128 + (bid0 >> 3);
    const int cc   = bid & 127;
    const int b    = bid >> 7;
    const int n0   = bid * 128;

    for (int i = tid; i < 400; i += 256)
        wct[i >> 4][i & 15] = dwc_w[(i & 15) * 25 + (i >> 4)];
    if (tid < 16) bi[tid] = dwc_b[tid];
    if (tid == 0) Gs = G[b * 128 + cc];
    __syncthreads();

    const int ch4 = tid >> 3;
    const int xg  = tid & 7;

    float acc[4][16];
#pragma unroll
    for (int c = 0; c < 4; ++c)
#pragma unroll
        for (int i = 0; i < 16; ++i) acc[c][i] = 0.f;

#pragma unroll
    for (int dy = 0; dy < 5; ++dy) {
        const int yy = cc + dy - 2;
        if (yy < 0 || yy > 127) continue;
#pragma unroll
        for (int c = 0; c < 4; ++c) {
            const int ch = ch4 * 4 + c;
            const unsigned short* rowp = kt + ((size_t)b * 128 + ch) * NN
                                            + yy * 128 + xg * 16 - 8;
            float wf[32];
#pragma unroll
            for (int q4 = 0; q4 < 4; ++q4) {
                const bf16x8 v = *(const bf16x8*)(rowp + q4 * 8);
#pragma unroll
                for (int e = 0; e < 8; ++e)
                    wf[q4 * 8 + e] = bf2f((unsigned short)v[e]);
            }
            if (xg == 0) {
#pragma unroll
                for (int e = 0; e < 8; ++e) wf[e] = 0.f;
            }
            if (xg == 7) {
#pragma unroll
                for (int e = 24; e < 32; ++e) wf[e] = 0.f;
            }
            const int d = ch & 15;
#pragma unroll
            for (int dx = 0; dx < 5; ++dx) {
                const float wv = wct[dy * 5 + dx][d];
#pragma unroll
                for (int i = 0; i < 16; ++i)
                    acc[c][i] += wv * wf[i + dx + 6];
            }
        }
    }

    const float Gcc = Gs;
    const unsigned short* kub = kt + ((size_t)b * 128 + cc) * NN;
    const float* zr = z + ((size_t)b * 8 + (cc >> 4)) * NN;
    const int dbase = (ch4 & 3) * 4;
    const float4 b4 = *(const float4*)(&bi[dbase]);
    const float bv[4] = {b4.x, b4.y, b4.z, b4.w};
#pragma unroll
    for (int i = 0; i < 16; ++i) {
        const int r = xg * 16 + i;
        const int toks = r * 128 + ch4 * 4;
        const short4v ku4 = *(const short4v*)(kub + toks);
        const float4 z4 = *(const float4*)(zr + toks);
        const float zz[4] = {z4.x, z4.y, z4.z, z4.w};
        short4v hv;
#pragma unroll
        for (int c = 0; c < 4; ++c) {
            const float f = Gcc * bf2f((unsigned short)ku4[c]) * zz[c] + acc[c][i] + bv[c];
            hv[c] = (short)f2bf(f);
        }
        const int swz = (((r & 7) ^ ((r >> 3) & 7)) << 4);
        const int ad = r * 256 + (((ch4 >> 1) * 16) ^ swz) + (ch4 & 1) * 8;
        *(short4v*)(smem + ad) = hv;
    }
    __syncthreads();

    const int w  = tid >> 6;
    const int ll = tid & 63;
    bf16x8 xh[2][4];
    {
        const int lg16 = (ll >> 4) * 16;
#pragma unroll
        for (int n = 0; n < 2; ++n) {
            const int r = w * 32 + n * 16 + (ll & 15);
            const int rb = r * 256;
            const int swz = (((r & 7) ^ ((r >> 3) & 7)) << 4);
#pragma unroll
            for (int kt2 = 0; kt2 < 4; ++kt2)
                xh[n][kt2] = *(bf16x8*)(smem + rb + ((kt2 * 64 + lg16) ^ swz));
        }
    }
    const int crow = (ll >> 4) * 4;
    f32x4 pacc[8][2];
#pragma unroll
    for (int m = 0; m < 8; ++m)
#pragma unroll
        for (int n = 0; n < 2; ++n) pacc[m][n] = (f32x4)0.f;

#pragma unroll
    for (int m = 0; m < 8; ++m) {
        const int c = m * 16 + (ll & 15);
        bf16x8 ah[4], al[4];
#pragma unroll
        for (int kt2 = 0; kt2 < 4; ++kt2) {
            const int off = 32768 + c * 128 + kt2 * 32 + (ll >> 4) * 8;
            ah[kt2] = *(const bf16x8*)(whi + off);
            al[kt2] = *(const bf16x8*)(wlo + off);
        }
#pragma unroll
        for (int n = 0; n < 2; ++n)
#pragma unroll
            for (int kt2 = 0; kt2 < 4; ++kt2) {
                pacc[m][n] = __builtin_amdgcn_mfma_f32_16x16x32_bf16(ah[kt2], xh[n][kt2], pacc[m][n], 0, 0, 0);
                pacc[m][n] = __builtin_amdgcn_mfma_f32_16x16x32_bf16(al[kt2], xh[n][kt2], pacc[m][n], 0, 0, 0);
            }
    }

#pragma unroll
    for (int m = 0; m < 8; ++m) {
        const float4 bq = *(const float4*)(bp + m * 16 + crow);
        const float bb[4] = {bq.x, bq.y, bq.z, bq.w};
#pragma unroll
        for (int n = 0; n < 2; ++n)
#pragma unroll
            for (int j = 0; j < 4; ++j) pacc[m][n][j] += bb[j];
    }
    __syncthreads();
#pragma unroll
    for (int n = 0; n < 2; ++n) {
        const int t = ll & 15;
        const int rb = w * 8192 + t * 512;
#pragma unroll
        for (int m = 0; m < 8; ++m) {
            const int ad = rb + (((m * 16 + crow) * 4) ^ ((t & 7) << 4));
            *(f32x4*)(smem + ad) = pacc[m][n];
        }
        asm volatile("s_waitcnt lgkmcnt(0)" ::: "memory");
#pragma unroll
        for (int j = 0; j < 8; ++j) {
            const int fid = j * 64 + ll;
            const int row = fid >> 5;
            const int c4  = fid & 31;
            const int rb3 = w * 8192 + row * 512;
            const f32x4 v = *(f32x4*)(smem + rb3 + ((c4 * 16) ^ ((row & 7) << 4)));
            *(f32x4*)(out + (n0 + w * 32 + n * 16 + row) * 128 + c4 * 4) = v;
        }
    }
}

// ---------------------------------------------------------------------------
extern "C" void kernel_launch(void* const* d_in, const int* in_sizes, int n_in,
                              void* d_out, int out_size, void* d_ws, size_t ws_size,
                              hipStream_t stream)
{
    const float* x       = (const float*)d_in[0];
    const float* Wq      = (const float*)d_in[1];
    const float* Wkv     = (const float*)d_in[2];
    const float* Wproj   = (const float*)d_in[3];
    const float* bproj   = (const float*)d_in[4];
    const float* w_g     = (const float*)d_in[5];
    const float* scale   = (const float*)d_in[6];
    const float* pos_enc = (const float*)d_in[7];
    const float* dwc_w   = (const float*)d_in[8];
    const float* dwc_b   = (const float*)d_in[9];
    float* out = (float*)d_out;

    // ktbuf deliberately NOT at offset 0 (scp conv halo under-reads 16B).
    char* ws = (char*)d_ws;
    float* partial1 = (float*)(ws);                           // 540672 B
    float* partial2 = (float*)(ws + 540672);                  // 524288 B
    float* G        = (float*)(ws + 1064960);                 // 4096 B
    float* kbar     = (float*)(ws + 1069056);                 // 4096 B
    unsigned short* whi = (unsigned short*)(ws + 1073152);    // 98304 B
    unsigned short* wlo = (unsigned short*)(ws + 1171456);    // 98304 B
    float* sps      = (float*)(ws + 1269760);                 // 512 B
    float* zbuf     = (float*)(ws + 1270272);                 // 4194304 B
    unsigned short* ktbuf = (unsigned short*)(ws + 5464576);  // 33554432 B

    wprep_kernel<<<dim3(49), dim3(256), 0, stream>>>(
        Wq, Wkv, Wproj, scale, whi, wlo, sps);
    kproj_kernel<<<dim3(1024), dim3(256), 0, stream>>>(
        x, whi, wlo, sps, pos_enc, ktbuf, partial2);
    reducek_kernel<<<dim3(8), dim3(1024), 0, stream>>>(partial2, kbar);
    qproj_kernel<<<dim3(1024), dim3(256), 0, stream>>>(
        x, whi, wlo, w_g, sps, kbar, zbuf, partial1);
    reduceg_kernel<<<dim3(8), dim3(1024), 0, stream>>>(partial1, G);
    scp_kernel<<<dim3(1024), dim3(256), 0, stream>>>(
        out, ktbuf, zbuf, G, whi, wlo, bproj, dwc_w, dwc_b);
}